// Round 5
// baseline (461.595 us; speedup 1.0000x reference)
//
#include <hip/hip_runtime.h>

#define BB 8
#define NN 4096
#define CC 256

typedef __attribute__((ext_vector_type(8))) short bfx8;
typedef __attribute__((ext_vector_type(4))) unsigned short usx4;
typedef __attribute__((ext_vector_type(4))) float fx4;
typedef _Float16 hfx8 __attribute__((ext_vector_type(8)));

__device__ inline unsigned short f2bf(float f) {
  union { float f; unsigned u; } c; c.f = f;
  unsigned r = c.u + 0x7fffu + ((c.u >> 16) & 1u);
  return (unsigned short)(r >> 16);
}
__device__ inline float bf2f(unsigned short h) {
  union { unsigned u; float f; } c; c.u = ((unsigned)h) << 16;
  return c.f;
}
__device__ inline unsigned short f2h(float f) {
  union { _Float16 h; unsigned short u; } c; c.h = (_Float16)f;
  return c.u;
}
__device__ inline fx4 MFMA(bfx8 a, bfx8 b, fx4 c) {
  return __builtin_amdgcn_mfma_f32_16x16x32_bf16(a, b, c, 0, 0, 0);
}
__device__ inline fx4 MFMAH(hfx8 a, hfx8 b, fx4 c) {
  return __builtin_amdgcn_mfma_f32_16x16x32_f16(a, b, c, 0, 0, 0);
}

// ---------------------------------------------------------------------------
// Kernel 0: transpose + hi/lo split the three weight matrices (bf16 parts).
// ---------------------------------------------------------------------------
__global__ void wconv(const float* __restrict__ Wq, const float* __restrict__ Wk,
                      const float* __restrict__ Wv,
                      unsigned short* __restrict__ Wth, unsigned short* __restrict__ Wtl) {
  int m = blockIdx.y, n = blockIdx.x, k = threadIdx.x;
  const float* W = (m == 0) ? Wq : (m == 1) ? Wk : Wv;
  float v = W[k * CC + n];
  unsigned short h = f2bf(v);
  unsigned short lo = f2bf(v - bf2f(h));
  int o = (m * CC + n) * CC + k;
  Wth[o] = h; Wtl[o] = lo;
}

// ---------------------------------------------------------------------------
// Kernel 1: projection GEMM  Out_m = X @ W_m  (M=32768, N=256, K=256)
// PASSES==3 (Q,K): split-bf16 3-pass MFMA, output single fp16 row-major.
// PASSES==1 (V):  1-pass bf16, output fp16 transposed per batch Vt[b][d][n].
// ---------------------------------------------------------------------------
template <int PASSES>
__global__ __launch_bounds__(256, 2) void proj(
    const float* __restrict__ x,
    const unsigned short* __restrict__ Wth, const unsigned short* __restrict__ Wtl,
    unsigned short* __restrict__ O0, unsigned short* __restrict__ O1) {
  __shared__ char lds[81920];
  const int m = (PASSES == 1) ? 2 : (int)blockIdx.y;
  const int row0 = blockIdx.x * 64;
  const int t = threadIdx.x;
  const int wv = t >> 6, l = t & 63, lg = l >> 4, ll = l & 15;

  fx4 acc[16];
#pragma unroll
  for (int i = 0; i < 16; ++i) acc[i] = (fx4){0.f, 0.f, 0.f, 0.f};

  const unsigned short* Wmh = Wth + m * CC * CC;
  const unsigned short* Wml = Wtl + m * CC * CC;

  for (int kc = 0; kc < 4; ++kc) {
    __syncthreads();
#pragma unroll
    for (int p = 0; p < 4; ++p) {
      int idx = p * 256 + t;
      int r = idx >> 4, c4 = (idx & 15) << 2;
      fx4 v = *(const fx4*)(x + (size_t)(row0 + r) * CC + kc * 64 + c4);
      usx4 hv, lv;
#pragma unroll
      for (int j = 0; j < 4; ++j) {
        unsigned short h = f2bf(v[j]);
        hv[j] = h;
        if (PASSES == 3) lv[j] = f2bf(v[j] - bf2f(h));
      }
      int bo = r * 128 + (((c4 << 1)) ^ ((r & 7) << 4));
      *(usx4*)(lds + bo) = hv;
      if (PASSES == 3) *(usx4*)(lds + 8192 + bo) = lv;
    }
#pragma unroll
    for (int p = 0; p < 8; ++p) {
      int idx = p * 256 + t;
      int n = idx >> 3, c8 = (idx & 7) << 3;
      int go = n * CC + kc * 64 + c8;
      bfx8 hv = *(const bfx8*)(Wmh + go);
      int bo = n * 128 + (((c8 << 1)) ^ ((n & 7) << 4));
      *(bfx8*)(lds + 16384 + bo) = hv;
      if (PASSES == 3) {
        bfx8 lv = *(const bfx8*)(Wml + go);
        *(bfx8*)(lds + 49152 + bo) = lv;
      }
    }
    __syncthreads();
#pragma unroll
    for (int ds = 0; ds < 2; ++ds) {
      int arow = wv * 16 + ll;
      int akb = ds * 64 + lg * 16;
      bfx8 ah = *(bfx8*)(lds + arow * 128 + (akb ^ ((arow & 7) << 4)));
      bfx8 al;
      if (PASSES == 3) al = *(bfx8*)(lds + 8192 + arow * 128 + (akb ^ ((arow & 7) << 4)));
#pragma unroll
      for (int nt = 0; nt < 16; ++nt) {
        int brow = nt * 16 + ll;
        int bo = brow * 128 + (akb ^ ((brow & 7) << 4));
        bfx8 bh = *(bfx8*)(lds + 16384 + bo);
        acc[nt] = MFMA(ah, bh, acc[nt]);
        if (PASSES == 3) {
          bfx8 bl = *(bfx8*)(lds + 49152 + bo);
          acc[nt] = MFMA(ah, bl, acc[nt]);
          acc[nt] = MFMA(al, bh, acc[nt]);
        }
      }
    }
  }
#pragma unroll
  for (int nt = 0; nt < 16; ++nt) {
#pragma unroll
    for (int r = 0; r < 4; ++r) {
      float v = acc[nt][r];
      int grow = row0 + wv * 16 + lg * 4 + r;
      int col = nt * 16 + ll;
      if (PASSES == 1) {
        int b = grow >> 12, nidx = grow & 4095;
        O0[(((size_t)(b * CC + col)) << 12) + nidx] = f2h(v);
      } else {
        size_t o = (size_t)grow * CC + col;
        (m == 0 ? O0 : O1)[o] = f2h(v);
      }
    }
  }
}

// ---------------------------------------------------------------------------
// Kernel 2: fused flash attention + gate, fp16 operands, fp32 accum.
// 256 thr (4 waves), 128 q-rows/block (32 per wave as 2 row-blocks of 16),
// KV tiles of 64 keys. Each LDS B-fragment read feeds 2 MFMAs (both row-
// blocks) -> per-CU LDS traffic halved vs 16-rows/wave. Grid 32x8 = 1
// block/CU. Per tile: reg->LDS stage (prefetched), 1-pass QK, online softmax
// w/ defer-max per row-block, P fp16 -> wave-local LDS, PV.
// LDS: K 4x[64key][64d] @0 (32K), Vt [256d][64key] @32768 (32K),
// P @65536 + wv*4096 (rb0 @+0, rb1 @+2048). 80KB total.
// ---------------------------------------------------------------------------
#define SOFTMAX(sacc, mrow, lrow, acco, pl)                                        \
  {                                                                                \
    float pm[4];                                                                   \
    _Pragma("unroll") for (int r = 0; r < 4; ++r)                                  \
      pm[r] = fmaxf(fmaxf(sacc[0][r], sacc[1][r]), fmaxf(sacc[2][r], sacc[3][r])); \
    _Pragma("unroll") for (int s = 1; s < 16; s <<= 1) {                           \
      _Pragma("unroll") for (int r = 0; r < 4; ++r)                                \
        pm[r] = fmaxf(pm[r], __shfl_xor(pm[r], s, 64));                            \
    }                                                                              \
    bool upd = false;                                                              \
    _Pragma("unroll") for (int r = 0; r < 4; ++r) upd |= (pm[r] > mrow[r] + 8.f);  \
    if (__any(upd)) {                                                              \
      _Pragma("unroll") for (int r = 0; r < 4; ++r) {                              \
        float mn = fmaxf(mrow[r], pm[r]);                                          \
        float scl = __expf(mrow[r] - mn);                                          \
        mrow[r] = mn; lrow[r] *= scl;                                              \
        _Pragma("unroll") for (int i = 0; i < 16; ++i) acco[i][r] *= scl;          \
      }                                                                            \
    }                                                                              \
    float rs[4] = {0.f, 0.f, 0.f, 0.f};                                            \
    _Pragma("unroll") for (int nt = 0; nt < 4; ++nt)                               \
      _Pragma("unroll") for (int r = 0; r < 4; ++r) {                              \
        float e = __expf(sacc[nt][r] - mrow[r]);                                   \
        rs[r] += e;                                                                \
        int prow = lg * 4 + r, pcol = nt * 16 + ll;                                \
        *(unsigned short*)((pl) + prow * 128 + (((pcol << 1)) ^ ((prow & 7) << 4))) = f2h(e); \
      }                                                                            \
    _Pragma("unroll") for (int s = 1; s < 16; s <<= 1) {                           \
      _Pragma("unroll") for (int r = 0; r < 4; ++r) rs[r] += __shfl_xor(rs[r], s, 64); \
    }                                                                              \
    _Pragma("unroll") for (int r = 0; r < 4; ++r) lrow[r] += rs[r];                \
  }

__global__ __launch_bounds__(256, 1) void attn(
    const float* __restrict__ x,
    const unsigned short* __restrict__ Qf, const unsigned short* __restrict__ Kf,
    const unsigned short* __restrict__ Vt, float* __restrict__ out) {
  __shared__ char lds[81920];
  const int b = blockIdx.y, q0 = blockIdx.x * 128;
  const int t = threadIdx.x, wv = t >> 6, l = t & 63, lg = l >> 4, ll = l & 15;

  // Q fragments for both row-blocks, in registers for the whole kernel
  hfx8 q0h[8], q1h[8];
  {
    int qrow = q0 + wv * 32 + ll;
    const unsigned short* p0 = Qf + ((size_t)(b * NN + qrow)) * CC + lg * 8;
    const unsigned short* p1 = p0 + (size_t)16 * CC;
#pragma unroll
    for (int ds = 0; ds < 8; ++ds) {
      q0h[ds] = *(const hfx8*)(p0 + ds * 32);
      q1h[ds] = *(const hfx8*)(p1 + ds * 32);
    }
  }

  fx4 accA[16], accB[16];
#pragma unroll
  for (int i = 0; i < 16; ++i) {
    accA[i] = (fx4){0.f, 0.f, 0.f, 0.f};
    accB[i] = (fx4){0.f, 0.f, 0.f, 0.f};
  }
  float m0[4] = {-1e30f, -1e30f, -1e30f, -1e30f};
  float m1[4] = {-1e30f, -1e30f, -1e30f, -1e30f};
  float l0[4] = {0.f, 0.f, 0.f, 0.f};
  float l1[4] = {0.f, 0.f, 0.f, 0.f};

  const unsigned short* Kb = Kf + (size_t)b * NN * CC;
  const unsigned short* Vtb = Vt + (size_t)b * CC * NN;
  char* pl0 = lds + 65536 + wv * 4096;
  char* pl1 = pl0 + 2048;

  // per-thread staging geometry
  const int kkey = t >> 5;         // key = p*8 + kkey
  const int kdb  = (t & 31) << 4;  // byte offset in 512B key row
  const int vd   = t >> 3;         // d = p*32 + vd
  const int vkb  = (t & 7) << 4;   // byte offset in 128B d row

  bfx8 kreg[8], vreg[8];  // prefetch registers (raw fp16 bits)
#pragma unroll
  for (int p = 0; p < 8; ++p) {
    kreg[p] = *(const bfx8*)((const char*)(Kb + (size_t)(p * 8 + kkey) * CC) + kdb);
    vreg[p] = *(const bfx8*)((const char*)(Vtb + (size_t)(p * 32 + vd) * NN) + vkb);
  }

  for (int kt = 0; kt < 64; ++kt) {
    __syncthreads();  // prev tile's LDS reads done; prefetch regs landed
#pragma unroll
    for (int p = 0; p < 8; ++p) {
      int key = p * 8 + kkey;
      *(bfx8*)(lds + (kdb >> 7) * 8192 + key * 128 + ((kdb & 127) ^ ((key & 7) << 4))) = kreg[p];
      int d = p * 32 + vd;
      *(bfx8*)(lds + 32768 + d * 128 + (vkb ^ ((d & 7) << 4))) = vreg[p];
    }
    __syncthreads();
    // issue next tile's global loads; they complete under this tile's compute
    if (kt < 63) {
      const unsigned short* Kn = Kb + (size_t)(kt + 1) * 64 * CC;
      const unsigned short* Vn = Vtb + (kt + 1) * 64;
#pragma unroll
      for (int p = 0; p < 8; ++p) {
        kreg[p] = *(const bfx8*)((const char*)(Kn + (size_t)(p * 8 + kkey) * CC) + kdb);
        vreg[p] = *(const bfx8*)((const char*)(Vn + (size_t)(p * 32 + vd) * NN) + vkb);
      }
    }
    // QK^T: each K fragment feeds both row-blocks
    fx4 s0[4], s1[4];
#pragma unroll
    for (int i = 0; i < 4; ++i) {
      s0[i] = (fx4){0.f, 0.f, 0.f, 0.f};
      s1[i] = (fx4){0.f, 0.f, 0.f, 0.f};
    }
    __builtin_amdgcn_s_setprio(1);
#pragma unroll
    for (int ds = 0; ds < 8; ++ds) {
      int dc = ds >> 1, dkb = (ds & 1) * 64 + lg * 16;
#pragma unroll
      for (int nt = 0; nt < 4; ++nt) {
        int krow = nt * 16 + ll;
        hfx8 bh = *(hfx8*)(lds + dc * 8192 + krow * 128 + (dkb ^ ((krow & 7) << 4)));
        s0[nt] = MFMAH(q0h[ds], bh, s0[nt]);
        s1[nt] = MFMAH(q1h[ds], bh, s1[nt]);
      }
    }
    __builtin_amdgcn_s_setprio(0);
    // online softmax per row-block (defer-max THR=8)
    SOFTMAX(s0, m0, l0, accA, pl0)
    SOFTMAX(s1, m1, l1, accB, pl1)
    // PV: each V fragment feeds both row-blocks
    __builtin_amdgcn_s_setprio(1);
#pragma unroll
    for (int ks = 0; ks < 2; ++ks) {
      int kbyte = ks * 64 + lg * 16;
      hfx8 pa0 = *(hfx8*)(pl0 + ll * 128 + (kbyte ^ ((ll & 7) << 4)));
      hfx8 pa1 = *(hfx8*)(pl1 + ll * 128 + (kbyte ^ ((ll & 7) << 4)));
#pragma unroll
      for (int nt = 0; nt < 16; ++nt) {
        int vrow = nt * 16 + ll;
        hfx8 bv = *(hfx8*)(lds + 32768 + vrow * 128 + (kbyte ^ ((vrow & 7) << 4)));
        accA[nt] = MFMAH(pa0, bv, accA[nt]);
        accB[nt] = MFMAH(pa1, bv, accB[nt]);
      }
    }
    __builtin_amdgcn_s_setprio(0);
  }
  // epilogue: normalize, gate with x, store fp32 (both row-blocks)
#pragma unroll
  for (int nt = 0; nt < 16; ++nt)
#pragma unroll
    for (int r = 0; r < 4; ++r) {
      int col = nt * 16 + ll;
      int g0 = q0 + wv * 32 + lg * 4 + r;
      size_t o0 = ((size_t)(b * NN + g0)) * CC + col;
      out[o0] = x[o0] * (accA[nt][r] / l0[r]);
      size_t o1 = o0 + (size_t)16 * CC;
      out[o1] = x[o1] * (accB[nt][r] / l1[r]);
    }
}

// ---------------------------------------------------------------------------
extern "C" void kernel_launch(void* const* d_in, const int* in_sizes, int n_in,
                              void* d_out, int out_size, void* d_ws, size_t ws_size,
                              hipStream_t stream) {
  const float* x  = (const float*)d_in[0];
  const float* Wq = (const float*)d_in[1];
  const float* Wk = (const float*)d_in[2];
  const float* Wv = (const float*)d_in[3];
  float* out = (float*)d_out;
  char* ws = (char*)d_ws;
  const size_t T = (size_t)BB * NN * CC * 2;  // 16 MiB per fp16 tensor
  unsigned short* Qf  = (unsigned short*)(ws);
  unsigned short* Kf  = (unsigned short*)(ws + T);
  unsigned short* Vt  = (unsigned short*)(ws + 2 * T);
  unsigned short* Wth = (unsigned short*)(ws + 3 * T);
  unsigned short* Wtl = (unsigned short*)(ws + 3 * T + (size_t)3 * CC * CC * 2);
  if (ws_size < 3 * T + (size_t)6 * CC * CC * 2) return;  // ~49 MB scratch

  hipLaunchKernelGGL(wconv, dim3(256, 3), dim3(256), 0, stream, Wq, Wk, Wv, Wth, Wtl);
  hipLaunchKernelGGL((proj<3>), dim3(512, 2), dim3(256), 0, stream, x, Wth, Wtl, Qf, Kf);
  hipLaunchKernelGGL((proj<1>), dim3(512, 1), dim3(256), 0, stream, x, Wth, Wtl, Vt, Vt);
  hipLaunchKernelGGL(attn, dim3(32, 8), dim3(256), 0, stream, x, Qf, Kf, Vt, out);
}

// Round 15
// 403.368 us; speedup vs baseline: 1.1444x; 1.1444x over previous
//
#include <hip/hip_runtime.h>

#define BB 8
#define NN 4096
#define CC 256

typedef __attribute__((ext_vector_type(8))) short bfx8;
typedef __attribute__((ext_vector_type(4))) unsigned short usx4;
typedef __attribute__((ext_vector_type(4))) float fx4;
typedef _Float16 hfx8 __attribute__((ext_vector_type(8)));

__device__ inline unsigned short f2bf(float f) {
  union { float f; unsigned u; } c; c.f = f;
  unsigned r = c.u + 0x7fffu + ((c.u >> 16) & 1u);
  return (unsigned short)(r >> 16);
}
__device__ inline float bf2f(unsigned short h) {
  union { unsigned u; float f; } c; c.u = ((unsigned)h) << 16;
  return c.f;
}
__device__ inline unsigned short f2h(float f) {
  union { _Float16 h; unsigned short u; } c; c.h = (_Float16)f;
  return c.u;
}
__device__ inline fx4 MFMA(bfx8 a, bfx8 b, fx4 c) {
  return __builtin_amdgcn_mfma_f32_16x16x32_bf16(a, b, c, 0, 0, 0);
}
__device__ inline fx4 MFMAH(hfx8 a, hfx8 b, fx4 c) {
  return __builtin_amdgcn_mfma_f32_16x16x32_f16(a, b, c, 0, 0, 0);
}

// ---------------------------------------------------------------------------
// Kernel 0: transpose + hi/lo split the three weight matrices (bf16 parts).
// ---------------------------------------------------------------------------
__global__ void wconv(const float* __restrict__ Wq, const float* __restrict__ Wk,
                      const float* __restrict__ Wv,
                      unsigned short* __restrict__ Wth, unsigned short* __restrict__ Wtl) {
  int m = blockIdx.y, n = blockIdx.x, k = threadIdx.x;
  const float* W = (m == 0) ? Wq : (m == 1) ? Wk : Wv;
  float v = W[k * CC + n];
  unsigned short h = f2bf(v);
  unsigned short lo = f2bf(v - bf2f(h));
  int o = (m * CC + n) * CC + k;
  Wth[o] = h; Wtl[o] = lo;
}

// ---------------------------------------------------------------------------
// Kernel 1: projection GEMM  Out_m = X @ W_m  (M=32768, N=256, K=256)
// PASSES==3 (Q,K): split-bf16 3-pass MFMA, output single fp16 row-major.
// PASSES==1 (V):  1-pass bf16, output fp16 transposed per batch Vt[b][d][n].
// ---------------------------------------------------------------------------
template <int PASSES>
__global__ __launch_bounds__(256, 2) void proj(
    const float* __restrict__ x,
    const unsigned short* __restrict__ Wth, const unsigned short* __restrict__ Wtl,
    unsigned short* __restrict__ O0, unsigned short* __restrict__ O1) {
  __shared__ char lds[81920];
  const int m = (PASSES == 1) ? 2 : (int)blockIdx.y;
  const int row0 = blockIdx.x * 64;
  const int t = threadIdx.x;
  const int wv = t >> 6, l = t & 63, lg = l >> 4, ll = l & 15;

  fx4 acc[16];
#pragma unroll
  for (int i = 0; i < 16; ++i) acc[i] = (fx4){0.f, 0.f, 0.f, 0.f};

  const unsigned short* Wmh = Wth + m * CC * CC;
  const unsigned short* Wml = Wtl + m * CC * CC;

  for (int kc = 0; kc < 4; ++kc) {
    __syncthreads();
#pragma unroll
    for (int p = 0; p < 4; ++p) {
      int idx = p * 256 + t;
      int r = idx >> 4, c4 = (idx & 15) << 2;
      fx4 v = *(const fx4*)(x + (size_t)(row0 + r) * CC + kc * 64 + c4);
      usx4 hv, lv;
#pragma unroll
      for (int j = 0; j < 4; ++j) {
        unsigned short h = f2bf(v[j]);
        hv[j] = h;
        if (PASSES == 3) lv[j] = f2bf(v[j] - bf2f(h));
      }
      int bo = r * 128 + (((c4 << 1)) ^ ((r & 7) << 4));
      *(usx4*)(lds + bo) = hv;
      if (PASSES == 3) *(usx4*)(lds + 8192 + bo) = lv;
    }
#pragma unroll
    for (int p = 0; p < 8; ++p) {
      int idx = p * 256 + t;
      int n = idx >> 3, c8 = (idx & 7) << 3;
      int go = n * CC + kc * 64 + c8;
      bfx8 hv = *(const bfx8*)(Wmh + go);
      int bo = n * 128 + (((c8 << 1)) ^ ((n & 7) << 4));
      *(bfx8*)(lds + 16384 + bo) = hv;
      if (PASSES == 3) {
        bfx8 lv = *(const bfx8*)(Wml + go);
        *(bfx8*)(lds + 49152 + bo) = lv;
      }
    }
    __syncthreads();
#pragma unroll
    for (int ds = 0; ds < 2; ++ds) {
      int arow = wv * 16 + ll;
      int akb = ds * 64 + lg * 16;
      bfx8 ah = *(bfx8*)(lds + arow * 128 + (akb ^ ((arow & 7) << 4)));
      bfx8 al;
      if (PASSES == 3) al = *(bfx8*)(lds + 8192 + arow * 128 + (akb ^ ((arow & 7) << 4)));
#pragma unroll
      for (int nt = 0; nt < 16; ++nt) {
        int brow = nt * 16 + ll;
        int bo = brow * 128 + (akb ^ ((brow & 7) << 4));
        bfx8 bh = *(bfx8*)(lds + 16384 + bo);
        acc[nt] = MFMA(ah, bh, acc[nt]);
        if (PASSES == 3) {
          bfx8 bl = *(bfx8*)(lds + 49152 + bo);
          acc[nt] = MFMA(ah, bl, acc[nt]);
          acc[nt] = MFMA(al, bh, acc[nt]);
        }
      }
    }
  }
#pragma unroll
  for (int nt = 0; nt < 16; ++nt) {
#pragma unroll
    for (int r = 0; r < 4; ++r) {
      float v = acc[nt][r];
      int grow = row0 + wv * 16 + lg * 4 + r;
      int col = nt * 16 + ll;
      if (PASSES == 1) {
        int b = grow >> 12, nidx = grow & 4095;
        O0[(((size_t)(b * CC + col)) << 12) + nidx] = f2h(v);
      } else {
        size_t o = (size_t)grow * CC + col;
        (m == 0 ? O0 : O1)[o] = f2h(v);
      }
    }
  }
}

// ---------------------------------------------------------------------------
// Kernel 2: fused flash attention + gate, fp16 operands, fp32 accum.
// R4 geometry restored: 256 thr (4 waves), 64 q-rows/block (16/wave),
// 2 blocks/CU. New: KV tiles of 32 keys with single-barrier LDS double-
// buffer (stage writes overlap compute), S^T swapped QK (per-lane scalar
// softmax state, 2-shuffle reductions, packed b64 P writes), conflict-
// optimal V swizzle. Loads for tile kt+2 issued one full tile ahead.
// LDS: buf0 K@0(16K) V@16K; buf1 K@32K V@48K; P @64K + wv*1K. 68K total.
// ---------------------------------------------------------------------------
#define LOADKV(K0)                                                            \
  {                                                                           \
    const unsigned short* Kn = Kb + (size_t)(K0) * CC;                        \
    const unsigned short* Vn = Vtb + (K0);                                    \
    _Pragma("unroll") for (int c = 0; c < 4; ++c) {                           \
      kreg[c] = *(const bfx8*)(Kn + (t >> 3) * CC + (t & 7) * 32 + c * 8);    \
      vreg[c] = *(const bfx8*)(Vn + (size_t)t * NN + c * 8);                  \
    }                                                                         \
  }

#define STAGE(kn, vn)                                                         \
  {                                                                           \
    _Pragma("unroll") for (int c = 0; c < 4; ++c) {                           \
      int db = (t & 7) * 64 + c * 16;                                         \
      *(bfx8*)((kn) + (db >> 7) * 4096 + (t >> 3) * 128 +                     \
               ((db & 127) ^ (((t >> 3) & 7) << 4))) = kreg[c];               \
      *(bfx8*)((vn) + t * 64 + ((c ^ (t & 3) ^ ((t >> 2) & 3)) << 4)) = vreg[c]; \
    }                                                                         \
  }

__global__ __launch_bounds__(256, 2) void attn(
    const float* __restrict__ x,
    const unsigned short* __restrict__ Qf, const unsigned short* __restrict__ Kf,
    const unsigned short* __restrict__ Vt, float* __restrict__ out) {
  __shared__ char lds[69632];
  const int b = blockIdx.y, q0 = blockIdx.x * 64;
  const int t = threadIdx.x, wv = t >> 6, l = t & 63, lg = l >> 4, ll = l & 15;

  // Q fragments in registers for the whole kernel (also valid as B-frags)
  hfx8 qh[8];
  {
    int qrow = q0 + wv * 16 + ll;
    const unsigned short* ph = Qf + ((size_t)(b * NN + qrow)) * CC + lg * 8;
#pragma unroll
    for (int ds = 0; ds < 8; ++ds) qh[ds] = *(const hfx8*)(ph + ds * 32);
  }

  fx4 acc_o[16];
#pragma unroll
  for (int i = 0; i < 16; ++i) acc_o[i] = (fx4){0.f, 0.f, 0.f, 0.f};
  float mrow = -1e30f, lrow = 0.f;  // per-lane scalars: this lane's q-row = ll

  const unsigned short* Kb = Kf + (size_t)b * NN * CC;
  const unsigned short* Vtb = Vt + (size_t)b * CC * NN;
  char* plds = lds + 65536 + wv * 1024;

  bfx8 kreg[4], vreg[4];
  LOADKV(0);
  STAGE(lds, lds + 16384);   // buf0 (compiler inserts vmcnt waits)
  LOADKV(32);                // tile 1 -> regs
  __syncthreads();

  for (int kt = 0; kt < 128; ++kt) {
    char* kb = lds + (kt & 1) * 32768;
    char* vb = kb + 16384;
    if (kt < 127) {
      char* kn = lds + ((kt & 1) ^ 1) * 32768;
      STAGE(kn, kn + 16384);              // tile kt+1 -> other buffer
      if (kt < 126) LOADKV((kt + 2) * 32);  // issue next loads, land next tile
    }
    // QK^T swapped: S^T = K·Q^T -> lane holds q-row ll, keys nt*16+lg*4+r
    fx4 sT[2];
    sT[0] = (fx4){0.f, 0.f, 0.f, 0.f};
    sT[1] = (fx4){0.f, 0.f, 0.f, 0.f};
    __builtin_amdgcn_s_setprio(1);
#pragma unroll
    for (int ds = 0; ds < 8; ++ds) {
      int db = ds * 64 + lg * 16;
#pragma unroll
      for (int nt = 0; nt < 2; ++nt) {
        int key = nt * 16 + ll;
        hfx8 af = *(hfx8*)(kb + (db >> 7) * 4096 + key * 128 +
                           ((db & 127) ^ ((key & 7) << 4)));
        sT[nt] = MFMAH(af, qh[ds], sT[nt]);
      }
    }
    __builtin_amdgcn_s_setprio(0);
    // ---- online softmax (per-lane row, reduce across lg via 2 shuffles) ----
    float pm = fmaxf(fmaxf(fmaxf(sT[0][0], sT[0][1]), fmaxf(sT[0][2], sT[0][3])),
                     fmaxf(fmaxf(sT[1][0], sT[1][1]), fmaxf(sT[1][2], sT[1][3])));
    pm = fmaxf(pm, __shfl_xor(pm, 16, 64));
    pm = fmaxf(pm, __shfl_xor(pm, 32, 64));
    if (__any(pm > mrow + 8.f)) {  // defer-max THR=8
      float mn = fmaxf(mrow, pm);
      float scl = __expf(mrow - mn);
      mrow = mn; lrow *= scl;
      // redistribute: acc_o reg r belongs to q-row lg*4+r; its scl lives in lane lg*4+r
      float s0 = __shfl(scl, lg * 4 + 0, 64);
      float s1 = __shfl(scl, lg * 4 + 1, 64);
      float s2 = __shfl(scl, lg * 4 + 2, 64);
      float s3 = __shfl(scl, lg * 4 + 3, 64);
#pragma unroll
      for (int i = 0; i < 16; ++i) {
        acc_o[i][0] *= s0; acc_o[i][1] *= s1; acc_o[i][2] *= s2; acc_o[i][3] *= s3;
      }
    }
    float rs = 0.f;
#pragma unroll
    for (int nt = 0; nt < 2; ++nt) {
      float e0 = __expf(sT[nt][0] - mrow);
      float e1 = __expf(sT[nt][1] - mrow);
      float e2 = __expf(sT[nt][2] - mrow);
      float e3 = __expf(sT[nt][3] - mrow);
      rs += (e0 + e1) + (e2 + e3);
      uint2 w;
      w.x = (unsigned)f2h(e0) | ((unsigned)f2h(e1) << 16);
      w.y = (unsigned)f2h(e2) | ((unsigned)f2h(e3) << 16);
      *(uint2*)(plds + ll * 64 + nt * 32 + lg * 8) = w;  // P[row ll][keys]
    }
    rs += __shfl_xor(rs, 16, 64);
    rs += __shfl_xor(rs, 32, 64);
    lrow += rs;
    // PV: A-frag P from wave-local LDS (K-dim = 32 keys), B from V tile
    hfx8 pa = *(hfx8*)(plds + ll * 64 + lg * 16);
    __builtin_amdgcn_s_setprio(1);
#pragma unroll
    for (int nt = 0; nt < 16; ++nt) {
      int d = nt * 16 + ll;
      hfx8 bv = *(hfx8*)(vb + d * 64 + ((lg ^ (d & 3) ^ ((d >> 2) & 3)) << 4));
      acc_o[nt] = MFMAH(pa, bv, acc_o[nt]);
    }
    __builtin_amdgcn_s_setprio(0);
    __syncthreads();  // buf[nxt] staged by all; buf[cur] reads done
  }
  // epilogue: fetch row sums for this lane's acc rows, normalize, gate, store
  float l0 = __shfl(lrow, lg * 4 + 0, 64);
  float l1 = __shfl(lrow, lg * 4 + 1, 64);
  float l2 = __shfl(lrow, lg * 4 + 2, 64);
  float l3 = __shfl(lrow, lg * 4 + 3, 64);
  fx4 linv = (fx4){1.f / l0, 1.f / l1, 1.f / l2, 1.f / l3};
#pragma unroll
  for (int nt = 0; nt < 16; ++nt)
#pragma unroll
    for (int r = 0; r < 4; ++r) {
      int grow = q0 + wv * 16 + lg * 4 + r;
      int col = nt * 16 + ll;
      size_t o = ((size_t)(b * NN + grow)) * CC + col;
      out[o] = x[o] * (acc_o[nt][r] * linv[r]);
    }
}

// ---------------------------------------------------------------------------
extern "C" void kernel_launch(void* const* d_in, const int* in_sizes, int n_in,
                              void* d_out, int out_size, void* d_ws, size_t ws_size,
                              hipStream_t stream) {
  const float* x  = (const float*)d_in[0];
  const float* Wq = (const float*)d_in[1];
  const float* Wk = (const float*)d_in[2];
  const float* Wv = (const float*)d_in[3];
  float* out = (float*)d_out;
  char* ws = (char*)d_ws;
  const size_t T = (size_t)BB * NN * CC * 2;  // 16 MiB per fp16 tensor
  unsigned short* Qf  = (unsigned short*)(ws);
  unsigned short* Kf  = (unsigned short*)(ws + T);
  unsigned short* Vt  = (unsigned short*)(ws + 2 * T);
  unsigned short* Wth = (unsigned short*)(ws + 3 * T);
  unsigned short* Wtl = (unsigned short*)(ws + 3 * T + (size_t)3 * CC * CC * 2);
  if (ws_size < 3 * T + (size_t)6 * CC * CC * 2) return;  // ~49 MB scratch

  hipLaunchKernelGGL(wconv, dim3(256, 3), dim3(256), 0, stream, Wq, Wk, Wv, Wth, Wtl);
  hipLaunchKernelGGL((proj<3>), dim3(512, 2), dim3(256), 0, stream, x, Wth, Wtl, Qf, Kf);
  hipLaunchKernelGGL((proj<1>), dim3(512, 1), dim3(256), 0, stream, x, Wth, Wtl, Vt, Vt);
  hipLaunchKernelGGL(attn, dim3(64, 8), dim3(256), 0, stream, x, Qf, Kf, Vt, out);
}